// Round 1
// baseline (724.777 us; speedup 1.0000x reference)
//
#include <hip/hip_runtime.h>
#include <math.h>

typedef unsigned short ushort_t;
typedef __attribute__((ext_vector_type(8))) short short8;
typedef __attribute__((ext_vector_type(4))) short short4v;
typedef __attribute__((ext_vector_type(4))) float f32x4;

#define B_ 64
#define C_ 64
#define T_ 512
#define V_ 25
#define K_ 3
#define O_ 64

__device__ __forceinline__ float hswish(float v) {
    return v * fminf(fmaxf(v + 3.0f, 0.0f), 6.0f) * (1.0f / 6.0f);
}
// round-to-nearest-even fp32 -> bf16 (values are finite, no NaN care)
__device__ __forceinline__ ushort_t f2bf(float f) {
    unsigned u = __float_as_uint(f);
    unsigned r = (u + 0x7FFFu + ((u >> 16) & 1u)) >> 16;
    return (ushort_t)r;
}
__device__ __forceinline__ float bf2f(ushort_t h) {
    return __uint_as_float(((unsigned)h) << 16);
}

// ---------------------------------------------------------------------------
// K0: build packed bf16 operands in workspace:
//   An2T[80][32]  : An2T[kw][v] = A_norm[k][v][w], kw=k*25+w (pad kw>=75, v>=25 -> 0)
//   W2  [64][192] : W2[o][k*64+c] = W_gcn[k][o][c] / 3
//   pw2 [64][64]  : pw2[o][c]    = tcn_pw[o][c]
// ---------------------------------------------------------------------------
__global__ void k0_prep(const float* __restrict__ Af, const float* __restrict__ Al,
                        const float* __restrict__ Wg, const float* __restrict__ pw,
                        ushort_t* __restrict__ An2T, ushort_t* __restrict__ W2,
                        ushort_t* __restrict__ pw2) {
    __shared__ float Aabs[K_ * V_ * V_];
    __shared__ float dsh[K_ * V_];
    int tid = threadIdx.x;
    for (int i = tid; i < K_ * V_ * V_; i += 256) Aabs[i] = fabsf(Af[i] + Al[i]);
    __syncthreads();
    for (int r = tid; r < K_ * V_; r += 256) {
        float s = 0.0f;
        for (int j = 0; j < V_; j++) s += Aabs[r * V_ + j];
        dsh[r] = rsqrtf(fmaxf(s, 1e-6f));
    }
    __syncthreads();
    for (int i = tid; i < 80 * 32; i += 256) {
        int kw = i >> 5, v = i & 31;
        float val = 0.0f;
        if (kw < 75 && v < 25) {
            int k = (kw >= 50) ? 2 : (kw >= 25 ? 1 : 0);
            int w = kw - k * 25;
            val = dsh[k * 25 + v] * Aabs[(k * 25 + v) * 25 + w] * dsh[k * 25 + w];
        }
        An2T[i] = f2bf(val);
    }
    for (int i = tid; i < 64 * 192; i += 256) {
        int o = i / 192, kc = i % 192;
        int k = kc >> 6, c = kc & 63;
        W2[i] = f2bf(Wg[(k * 64 + o) * 64 + c] * (1.0f / 3.0f));
    }
    for (int i = tid; i < 64 * 64; i += 256) pw2[i] = f2bf(pw[i]);
}

// ---------------------------------------------------------------------------
// K1: GCN, full MFMA. One block = one (b, 4 t's). 256 threads = 4 waves.
// stage1: xa[(c,t) 256 x kw 80] = x-tile[256 x 32pad] @ An2[32 x 80]   (MFMA, 16 Mt x 5 Nt)
//         -> LDS xa2[tw 100][kc 192 (+8 pad)] bf16
// stage2: y[o 64 x tw 100] = W2[64 x 192] @ xa2[192 x tw]              (MFMA, 4 Mt x 7 Nt x 6 Kt)
//         epilogue BN+hswish -> y bf16 [b][tv][o]
// LDS 40.0 KB -> 4 blocks/CU (was 44.8 KB / 3 blocks).
// ---------------------------------------------------------------------------
__global__ __launch_bounds__(256, 4) void k1_gcn(
    const float* __restrict__ x, const ushort_t* __restrict__ An2T,
    const ushort_t* __restrict__ W2, const float* __restrict__ gs,
    const float* __restrict__ gb, ushort_t* __restrict__ y) {
    __shared__ ushort_t xa2[100 * 200];   // 40.0 KB -> 4 blocks/CU

    int bid = blockIdx.x;
    int b = bid >> 7;
    int t0 = (bid & 127) * 4;
    int tid = threadIdx.x;
    int wave = tid >> 6, lane = tid & 63;
    int m16 = lane & 15, g = lane >> 4;

    // register-resident B-frags of An2 (5 N-tiles): B[v=g*8+j][kw=n*16+m16]
    short8 bfA[5];
#pragma unroll
    for (int n = 0; n < 5; n++)
        bfA[n] = *(const short8*)(An2T + (n * 16 + m16) * 32 + g * 8);

    // ---- stage 1 ----
    int v0 = g * 8;
    for (int mt = 0; mt < 4; mt++) {
        int Mt = wave * 4 + mt;
        int ct = Mt * 16 + m16;          // row index = c*4 + t
        int c = ct >> 2, t = ct & 3;
        const float* gx = x + ((size_t)(b * 64 + c) * 512 + t0 + t) * 25;
        short8 af;
#pragma unroll
        for (int j = 0; j < 8; j++) {
            int v = v0 + j;
            float f = (v < 25) ? gx[v] : 0.0f;
            af[j] = (short)f2bf(f);
        }
        f32x4 acc[5];
#pragma unroll
        for (int n = 0; n < 5; n++) {
            acc[n] = (f32x4){0.f, 0.f, 0.f, 0.f};
            acc[n] = __builtin_amdgcn_mfma_f32_16x16x32_bf16(af, bfA[n], acc[n], 0, 0, 0);
        }
        // D layout: col kw = n*16+m16, row ct = Mt*16 + g*4 + r  => c = Mt*4+g, t = r
        int cc = Mt * 4 + g;
#pragma unroll
        for (int n = 0; n < 5; n++) {
            int kw = n * 16 + m16;
            if (kw < 75) {
                int k = (kw >= 50) ? 2 : (kw >= 25 ? 1 : 0);
                int w = kw - k * 25;
#pragma unroll
                for (int r = 0; r < 4; r++)
                    xa2[(r * 25 + w) * 200 + k * 64 + cc] = f2bf(acc[r < 4 ? n : n][r]);
            }
        }
    }
    __syncthreads();

    // ---- stage 2 ----
    // load A-frags of W2 after the barrier to cut stage-1 register pressure
    short8 afW[6];
#pragma unroll
    for (int kt = 0; kt < 6; kt++)
        afW[kt] = *(const short8*)(W2 + (wave * 16 + m16) * 192 + kt * 32 + g * 8);
    f32x4 gs4 = *(const f32x4*)(gs + wave * 16 + g * 4);
    f32x4 gb4 = *(const f32x4*)(gb + wave * 16 + g * 4);
    for (int nt = 0; nt < 7; nt++) {
        int tw = nt * 16 + m16;
        int twr = (tw < 100) ? tw : 99;   // clamped read; garbage cols masked at store
        f32x4 acc = (f32x4){0.f, 0.f, 0.f, 0.f};
#pragma unroll
        for (int kt = 0; kt < 6; kt++) {
            short8 bf = *(const short8*)(xa2 + twr * 200 + kt * 32 + g * 8);
            acc = __builtin_amdgcn_mfma_f32_16x16x32_bf16(afW[kt], bf, acc, 0, 0, 0);
        }
        if (tw < 100) {
            short4v pack;
#pragma unroll
            for (int r = 0; r < 4; r++) {
                float z = acc[r] * gs4[r] + gb4[r];
                pack[r] = (short)f2bf(hswish(z));
            }
            // y bf16 layout [b][tv][o], o = wave*16 + g*4 + r (4 consecutive)
            *(short4v*)(y + ((size_t)b * 12800 + t0 * 25 + tw) * 64 + wave * 16 + g * 4) = pack;
        }
    }
}

// ---------------------------------------------------------------------------
// K2: TCN. One block = one (b, 8 t's). 256 threads = 4 waves.
// phase A: stage y window (16 t x 25 v rows, pitch 64) to LDS (b128, zero halo)
// phase B: depthwise k=9 + BN1 + hswish in registers (4 ch/thread, b64 reads)
// phase C: th overwrites same LDS buffer [tv 200][64] bf16
// phase D: pointwise 64x64 MFMA + BN2 + residual + hswish -> out fp32
// LDS 51.2 KB -> 3 blocks/CU (was 57.6 KB / 2 blocks). Pitch 64 keeps 16B
// alignment for b128; phases A/B/C remain at the LDS bank floor, phase D's
// 26 b128 reads take a ~2x bank conflict (accepted for +50% occupancy).
// ---------------------------------------------------------------------------
__global__ __launch_bounds__(256, 3) void k2_tcn(
    const ushort_t* __restrict__ y, const float* __restrict__ x,
    const float* __restrict__ dw, const ushort_t* __restrict__ pw2,
    const float* __restrict__ s1v, const float* __restrict__ b1v,
    const float* __restrict__ s2v, const float* __restrict__ b2v,
    float* __restrict__ out) {
    __shared__ ushort_t ys[400 * 64];   // 51.2 KB -> 3 blocks/CU (reused for th)

    int bid = blockIdx.x;
    int b = bid >> 6;
    int t0 = (bid & 63) * 8;
    int tid = threadIdx.x;
    int wave = tid >> 6, lane = tid & 63;
    int m16 = lane & 15, g = lane >> 4;

    // ---- phase A: stage window rows [t0*25-100, t0*25+300) ----
    const ushort_t* yb = y + (size_t)b * 12800 * 64;
    int tvbase = t0 * 25 - 100;
#pragma unroll
    for (int i = 0; i < 13; i++) {
        int li = tid + 256 * i;          // 3200 x short8 total
        if (li < 3200) {
            int row = li >> 3;
            int col = (li & 7) * 8;
            int tvg = tvbase + row;
            short8 val = (short8){0, 0, 0, 0, 0, 0, 0, 0};
            if (tvg >= 0 && tvg < 12800)
                val = *(const short8*)(yb + (size_t)tvg * 64 + col);
            *(short8*)(ys + row * 64 + col) = val;
        }
    }
    __syncthreads();

    // ---- phase B: depthwise into registers ----
    int cg = tid & 15, c0 = cg * 4;
    float dwc[4][9], s1r[4], b1r[4];
#pragma unroll
    for (int cj = 0; cj < 4; cj++) {
#pragma unroll
        for (int dt = 0; dt < 9; dt++) dwc[cj][dt] = dw[(c0 + cj) * 9 + dt];
        s1r[cj] = s1v[c0 + cj];
        b1r[cj] = b1v[c0 + cj];
    }
    short4v thv[13];
#pragma unroll
    for (int i = 0; i < 13; i++) {
        int tv = (tid >> 4) + 16 * i;
        float a0 = 0, a1 = 0, a2 = 0, a3 = 0;
        if (tv < 200) {
#pragma unroll
            for (int dt = 0; dt < 9; dt++) {
                short4v yv = *(const short4v*)(ys + (tv + dt * 25) * 64 + c0);
                a0 += dwc[0][dt] * bf2f((ushort_t)yv[0]);
                a1 += dwc[1][dt] * bf2f((ushort_t)yv[1]);
                a2 += dwc[2][dt] * bf2f((ushort_t)yv[2]);
                a3 += dwc[3][dt] * bf2f((ushort_t)yv[3]);
            }
        }
        short4v p;
        p[0] = (short)f2bf(hswish(a0 * s1r[0] + b1r[0]));
        p[1] = (short)f2bf(hswish(a1 * s1r[1] + b1r[1]));
        p[2] = (short)f2bf(hswish(a2 * s1r[2] + b1r[2]));
        p[3] = (short)f2bf(hswish(a3 * s1r[3] + b1r[3]));
        thv[i] = p;
    }
    __syncthreads();   // all ys reads complete before overwrite

    // ---- phase C: th[tv][64] into same buffer ----
#pragma unroll
    for (int i = 0; i < 13; i++) {
        int tv = (tid >> 4) + 16 * i;
        if (tv < 200) *(short4v*)(ys + tv * 64 + c0) = thv[i];
    }
    __syncthreads();

    // ---- phase D: pointwise MFMA + epilogue ----
    short8 afP[2];
#pragma unroll
    for (int kt = 0; kt < 2; kt++)
        afP[kt] = *(const short8*)(pw2 + (wave * 16 + m16) * 64 + kt * 32 + g * 8);
    f32x4 s2_4 = *(const f32x4*)(s2v + wave * 16 + g * 4);
    f32x4 b2_4 = *(const f32x4*)(b2v + wave * 16 + g * 4);
    for (int nt = 0; nt < 13; nt++) {
        int tw = nt * 16 + m16;
        int twc = (tw < 200) ? tw : 199;   // clamped read; garbage cols masked at store
        f32x4 acc = (f32x4){0.f, 0.f, 0.f, 0.f};
#pragma unroll
        for (int kt = 0; kt < 2; kt++) {
            short8 bf = *(const short8*)(ys + twc * 64 + kt * 32 + g * 8);
            acc = __builtin_amdgcn_mfma_f32_16x16x32_bf16(afP[kt], bf, acc, 0, 0, 0);
        }
        if (tw < 200) {
#pragma unroll
            for (int r = 0; r < 4; r++) {
                int o = wave * 16 + g * 4 + r;
                size_t idx = (size_t)(b * 64 + o) * 12800 + t0 * 25 + tw;
                float z = acc[r] * s2_4[r] + b2_4[r] + x[idx];
                out[idx] = hswish(z);
            }
        }
    }
}

extern "C" void kernel_launch(void* const* d_in, const int* in_sizes, int n_in,
                              void* d_out, int out_size, void* d_ws, size_t ws_size,
                              hipStream_t stream) {
    const float* x   = (const float*)d_in[0];
    const float* Af  = (const float*)d_in[1];
    const float* Al  = (const float*)d_in[2];
    const float* Wg  = (const float*)d_in[3];
    const float* gs  = (const float*)d_in[4];
    const float* gb  = (const float*)d_in[5];
    const float* dw  = (const float*)d_in[6];
    const float* pw  = (const float*)d_in[7];
    const float* s1v = (const float*)d_in[8];
    const float* b1v = (const float*)d_in[9];
    const float* s2v = (const float*)d_in[10];
    const float* b2v = (const float*)d_in[11];
    float* out = (float*)d_out;

    ushort_t* An2T = (ushort_t*)d_ws;                       // 80*32
    ushort_t* W2   = An2T + 2560;                           // 64*192
    ushort_t* pw2  = W2 + 12288;                            // 64*64
    ushort_t* ybf  = (ushort_t*)((char*)d_ws + 65536);      // 64*12800*64 bf16 (~105 MB)

    k0_prep<<<1, 256, 0, stream>>>(Af, Al, Wg, pw, An2T, W2, pw2);
    k1_gcn<<<B_ * (T_ / 4), 256, 0, stream>>>(x, An2T, W2, gs, gb, ybf);
    k2_tcn<<<B_ * (T_ / 8), 256, 0, stream>>>(ybf, x, dw, pw2, s1v, b1v, s2v, b2v, out);
}

// Round 2
// 708.459 us; speedup vs baseline: 1.0230x; 1.0230x over previous
//
#include <hip/hip_runtime.h>
#include <math.h>

typedef unsigned short ushort_t;
typedef __attribute__((ext_vector_type(8))) short short8;
typedef __attribute__((ext_vector_type(4))) short short4v;
typedef __attribute__((ext_vector_type(4))) float f32x4;

#define B_ 64
#define C_ 64
#define T_ 512
#define V_ 25
#define K_ 3
#define O_ 64

__device__ __forceinline__ float hswish(float v) {
    return v * fminf(fmaxf(v + 3.0f, 0.0f), 6.0f) * (1.0f / 6.0f);
}
// round-to-nearest-even fp32 -> bf16 (values are finite, no NaN care)
__device__ __forceinline__ ushort_t f2bf(float f) {
    unsigned u = __float_as_uint(f);
    unsigned r = (u + 0x7FFFu + ((u >> 16) & 1u)) >> 16;
    return (ushort_t)r;
}
__device__ __forceinline__ float bf2f(ushort_t h) {
    return __uint_as_float(((unsigned)h) << 16);
}

// ---------------------------------------------------------------------------
// K0: build packed bf16 operands in workspace:
//   An2T[80][32]  : An2T[kw][v] = A_norm[k][v][w], kw=k*25+w (pad kw>=75, v>=25 -> 0)
//   W2  [64][192] : W2[o][k*64+c] = W_gcn[k][o][c] / 3
//   pw2 [64][64]  : pw2[o][c]    = tcn_pw[o][c]
// ---------------------------------------------------------------------------
__global__ void k0_prep(const float* __restrict__ Af, const float* __restrict__ Al,
                        const float* __restrict__ Wg, const float* __restrict__ pw,
                        ushort_t* __restrict__ An2T, ushort_t* __restrict__ W2,
                        ushort_t* __restrict__ pw2) {
    __shared__ float Aabs[K_ * V_ * V_];
    __shared__ float dsh[K_ * V_];
    int tid = threadIdx.x;
    for (int i = tid; i < K_ * V_ * V_; i += 256) Aabs[i] = fabsf(Af[i] + Al[i]);
    __syncthreads();
    for (int r = tid; r < K_ * V_; r += 256) {
        float s = 0.0f;
        for (int j = 0; j < V_; j++) s += Aabs[r * V_ + j];
        dsh[r] = rsqrtf(fmaxf(s, 1e-6f));
    }
    __syncthreads();
    for (int i = tid; i < 80 * 32; i += 256) {
        int kw = i >> 5, v = i & 31;
        float val = 0.0f;
        if (kw < 75 && v < 25) {
            int k = (kw >= 50) ? 2 : (kw >= 25 ? 1 : 0);
            int w = kw - k * 25;
            val = dsh[k * 25 + v] * Aabs[(k * 25 + v) * 25 + w] * dsh[k * 25 + w];
        }
        An2T[i] = f2bf(val);
    }
    for (int i = tid; i < 64 * 192; i += 256) {
        int o = i / 192, kc = i % 192;
        int k = kc >> 6, c = kc & 63;
        W2[i] = f2bf(Wg[(k * 64 + o) * 64 + c] * (1.0f / 3.0f));
    }
    for (int i = tid; i < 64 * 64; i += 256) pw2[i] = f2bf(pw[i]);
}

// ---------------------------------------------------------------------------
// K1: GCN, full MFMA. One block = one (b, 4 t's). 256 threads = 4 waves.
// stage0: x tile (64 c x 100 floats, contiguous per c) -> LDS via float4 (coalesced)
// stage1: af frags from LDS; xa[(c,t) 256 x kw 80] = x-tile @ An2  (MFMA)
//         -> LDS xa2[tw 100][kc 192 (+8 pad)] bf16 (overlays stage0 buffer)
// stage2: y[o 64 x tw 100] = W2[64 x 192] @ xa2[192 x tw]  (MFMA), BN+hswish
// LDS 40.0 KB. No forced min-occupancy (avoid VGPR-cap spill risk).
// ---------------------------------------------------------------------------
__global__ __launch_bounds__(256) void k1_gcn(
    const float* __restrict__ x, const ushort_t* __restrict__ An2T,
    const ushort_t* __restrict__ W2, const float* __restrict__ gs,
    const float* __restrict__ gb, ushort_t* __restrict__ y) {
    __shared__ ushort_t xa2[100 * 200];   // 40.0 KB (overlaid: first 25.6 KB = xs)
    float* xs = (float*)xa2;              // [64 c][100 floats]

    int bid = blockIdx.x;
    int b = bid >> 7;
    int t0 = (bid & 127) * 4;
    int tid = threadIdx.x;
    int wave = tid >> 6, lane = tid & 63;
    int m16 = lane & 15, g = lane >> 4;

    // ---- stage 0: coalesced x -> LDS (1600 float4; perfectly sequential LDS) ----
#pragma unroll
    for (int i = 0; i < 7; i++) {
        int li = tid + 256 * i;
        if (li < 1600) {
            int c = li / 25, f4 = li % 25;
            const float* src = x + ((size_t)(b * 64 + c) * 512 + t0) * 25 + f4 * 4;
            *(f32x4*)(xs + c * 100 + f4 * 4) = *(const f32x4*)src;
        }
    }

    // register-resident B-frags of An2 (5 N-tiles): B[v=g*8+j][kw=n*16+m16]
    short8 bfA[5];
#pragma unroll
    for (int n = 0; n < 5; n++)
        bfA[n] = *(const short8*)(An2T + (n * 16 + m16) * 32 + g * 8);

    __syncthreads();

    // ---- read all A-frags from LDS BEFORE xa2 overwrites the buffer ----
    int v0 = g * 8;
    short8 af[4];
#pragma unroll
    for (int mt = 0; mt < 4; mt++) {
        int ct = (wave * 4 + mt) * 16 + m16;   // row = c*4 + t, addr = 25*ct + v
#pragma unroll
        for (int j = 0; j < 8; j++) {
            int v = v0 + j;
            float f = (v < 25) ? xs[25 * ct + v] : 0.0f;
            af[mt][j] = (short)f2bf(f);
        }
    }
    __syncthreads();   // xs dead; xa2 region may be written

    // ---- stage 1: MFMA + scatter to xa2 ----
#pragma unroll
    for (int mt = 0; mt < 4; mt++) {
        int Mt = wave * 4 + mt;
        f32x4 acc[5];
#pragma unroll
        for (int n = 0; n < 5; n++) {
            acc[n] = (f32x4){0.f, 0.f, 0.f, 0.f};
            acc[n] = __builtin_amdgcn_mfma_f32_16x16x32_bf16(af[mt], bfA[n], acc[n], 0, 0, 0);
        }
        // D layout: col kw = n*16+m16, row ct = Mt*16 + g*4 + r  => c = Mt*4+g, t = r
        int cc = Mt * 4 + g;
#pragma unroll
        for (int n = 0; n < 5; n++) {
            int kw = n * 16 + m16;
            if (kw < 75) {
                int k = (kw >= 50) ? 2 : (kw >= 25 ? 1 : 0);
                int w = kw - k * 25;
#pragma unroll
                for (int r = 0; r < 4; r++)
                    xa2[(r * 25 + w) * 200 + k * 64 + cc] = f2bf(acc[n][r]);
            }
        }
    }
    __syncthreads();

    // ---- stage 2 ----
    short8 afW[6];
#pragma unroll
    for (int kt = 0; kt < 6; kt++)
        afW[kt] = *(const short8*)(W2 + (wave * 16 + m16) * 192 + kt * 32 + g * 8);
    f32x4 gs4 = *(const f32x4*)(gs + wave * 16 + g * 4);
    f32x4 gb4 = *(const f32x4*)(gb + wave * 16 + g * 4);
    for (int nt = 0; nt < 7; nt++) {
        int tw = nt * 16 + m16;
        int twr = (tw < 100) ? tw : 99;   // clamped read; garbage cols masked at store
        f32x4 acc = (f32x4){0.f, 0.f, 0.f, 0.f};
#pragma unroll
        for (int kt = 0; kt < 6; kt++) {
            short8 bf = *(const short8*)(xa2 + twr * 200 + kt * 32 + g * 8);
            acc = __builtin_amdgcn_mfma_f32_16x16x32_bf16(afW[kt], bf, acc, 0, 0, 0);
        }
        if (tw < 100) {
            short4v pack;
#pragma unroll
            for (int r = 0; r < 4; r++) {
                float z = acc[r] * gs4[r] + gb4[r];
                pack[r] = (short)f2bf(hswish(z));
            }
            // y bf16 layout [b][tv][o], o = wave*16 + g*4 + r (4 consecutive)
            *(short4v*)(y + ((size_t)b * 12800 + t0 * 25 + tw) * 64 + wave * 16 + g * 4) = pack;
        }
    }
}

// ---------------------------------------------------------------------------
// K2: TCN. One block = one (b, 8 t's). 256 threads = 4 waves.
// phase A: stage y window (16 t x 25 v rows, pitch 64) to LDS (b128, zero halo)
// phase B: depthwise k=9 + BN1 + hswish in registers (4 ch/thread, b64 reads)
// phase C: th overwrites same LDS buffer [tv 200][64] bf16
// phase D: pointwise 64x64 MFMA, all 13 accs held in registers
// phase E: BN2-scaled accs -> fp32 LDS transpose [o 64][tv pitch 204] (2-way banks,
//          free), then coalesced float4 readback + float4 residual + float4 store.
// LDS 52.2 KB -> 3 blocks/CU.  Fixes the 2.9x WRITE_SIZE amplification of the
// previous scalar scattered epilogue (597 MB -> ~215 MB).
// ---------------------------------------------------------------------------
__global__ __launch_bounds__(256, 3) void k2_tcn(
    const ushort_t* __restrict__ y, const float* __restrict__ x,
    const float* __restrict__ dw, const ushort_t* __restrict__ pw2,
    const float* __restrict__ s1v, const float* __restrict__ b1v,
    const float* __restrict__ s2v, const float* __restrict__ b2v,
    float* __restrict__ out) {
    __shared__ f32x4 smemv[3264];            // 52224 B, 16B aligned
    ushort_t* ys = (ushort_t*)smemv;         // [400][64] bf16 = 51200 B
    float* fb = (float*)smemv;               // [64][204] fp32 = 52224 B

    int bid = blockIdx.x;
    int b = bid >> 6;
    int t0 = (bid & 63) * 8;
    int tid = threadIdx.x;
    int wave = tid >> 6, lane = tid & 63;
    int m16 = lane & 15, g = lane >> 4;

    // ---- phase A: stage window rows [t0*25-100, t0*25+300) ----
    const ushort_t* yb = y + (size_t)b * 12800 * 64;
    int tvbase = t0 * 25 - 100;
#pragma unroll
    for (int i = 0; i < 13; i++) {
        int li = tid + 256 * i;          // 3200 x short8 total
        if (li < 3200) {
            int row = li >> 3;
            int col = (li & 7) * 8;
            int tvg = tvbase + row;
            short8 val = (short8){0, 0, 0, 0, 0, 0, 0, 0};
            if (tvg >= 0 && tvg < 12800)
                val = *(const short8*)(yb + (size_t)tvg * 64 + col);
            *(short8*)(ys + row * 64 + col) = val;
        }
    }
    __syncthreads();

    // ---- phase B: depthwise into registers ----
    int cg = tid & 15, c0 = cg * 4;
    float dwc[4][9], s1r[4], b1r[4];
#pragma unroll
    for (int cj = 0; cj < 4; cj++) {
#pragma unroll
        for (int dt = 0; dt < 9; dt++) dwc[cj][dt] = dw[(c0 + cj) * 9 + dt];
        s1r[cj] = s1v[c0 + cj];
        b1r[cj] = b1v[c0 + cj];
    }
    short4v thv[13];
#pragma unroll
    for (int i = 0; i < 13; i++) {
        int tv = (tid >> 4) + 16 * i;
        float a0 = 0, a1 = 0, a2 = 0, a3 = 0;
        if (tv < 200) {
#pragma unroll
            for (int dt = 0; dt < 9; dt++) {
                short4v yv = *(const short4v*)(ys + (tv + dt * 25) * 64 + c0);
                a0 += dwc[0][dt] * bf2f((ushort_t)yv[0]);
                a1 += dwc[1][dt] * bf2f((ushort_t)yv[1]);
                a2 += dwc[2][dt] * bf2f((ushort_t)yv[2]);
                a3 += dwc[3][dt] * bf2f((ushort_t)yv[3]);
            }
        }
        short4v p;
        p[0] = (short)f2bf(hswish(a0 * s1r[0] + b1r[0]));
        p[1] = (short)f2bf(hswish(a1 * s1r[1] + b1r[1]));
        p[2] = (short)f2bf(hswish(a2 * s1r[2] + b1r[2]));
        p[3] = (short)f2bf(hswish(a3 * s1r[3] + b1r[3]));
        thv[i] = p;
    }
    __syncthreads();   // all ys reads complete before overwrite

    // ---- phase C: th[tv][64] into same buffer ----
#pragma unroll
    for (int i = 0; i < 13; i++) {
        int tv = (tid >> 4) + 16 * i;
        if (tv < 200) *(short4v*)(ys + tv * 64 + c0) = thv[i];
    }
    __syncthreads();

    // ---- phase D: pointwise MFMA, accs stay in registers ----
    short8 afP[2];
#pragma unroll
    for (int kt = 0; kt < 2; kt++)
        afP[kt] = *(const short8*)(pw2 + (wave * 16 + m16) * 64 + kt * 32 + g * 8);
    f32x4 s2_4 = *(const f32x4*)(s2v + wave * 16 + g * 4);
    f32x4 b2_4 = *(const f32x4*)(b2v + wave * 16 + g * 4);
    f32x4 accs[13];
#pragma unroll
    for (int nt = 0; nt < 13; nt++) {
        int tw = nt * 16 + m16;
        int twc = (tw < 200) ? tw : 199;   // clamped read; masked at phase E
        f32x4 acc = (f32x4){0.f, 0.f, 0.f, 0.f};
#pragma unroll
        for (int kt = 0; kt < 2; kt++) {
            short8 bf = *(const short8*)(ys + twc * 64 + kt * 32 + g * 8);
            acc = __builtin_amdgcn_mfma_f32_16x16x32_bf16(afP[kt], bf, acc, 0, 0, 0);
        }
        accs[nt] = acc;
    }
    __syncthreads();   // all ys reads done; fb may overwrite

    // ---- phase E1: BN2-scaled accs -> fp32 transpose buffer fb[o][tv] ----
#pragma unroll
    for (int nt = 0; nt < 13; nt++) {
        int tw = nt * 16 + m16;
        if (tw < 200) {
#pragma unroll
            for (int r = 0; r < 4; r++)
                fb[(wave * 16 + g * 4 + r) * 204 + tw] = accs[nt][r] * s2_4[r] + b2_4[r];
        }
    }
    __syncthreads();

    // ---- phase E2: coalesced readback + residual + store (3200 float4) ----
#pragma unroll
    for (int i = 0; i < 13; i++) {
        int l = tid + 256 * i;
        if (l < 3200) {
            int o = l / 50, c4 = l % 50;
            f32x4 v = *(const f32x4*)(fb + o * 204 + c4 * 4);
            size_t gi = (size_t)(b * 64 + o) * 12800 + t0 * 25 + c4 * 4;
            f32x4 xr = *(const f32x4*)(x + gi);
            f32x4 res;
#pragma unroll
            for (int r = 0; r < 4; r++) res[r] = hswish(v[r] + xr[r]);
            *(f32x4*)(out + gi) = res;
        }
    }
}

extern "C" void kernel_launch(void* const* d_in, const int* in_sizes, int n_in,
                              void* d_out, int out_size, void* d_ws, size_t ws_size,
                              hipStream_t stream) {
    const float* x   = (const float*)d_in[0];
    const float* Af  = (const float*)d_in[1];
    const float* Al  = (const float*)d_in[2];
    const float* Wg  = (const float*)d_in[3];
    const float* gs  = (const float*)d_in[4];
    const float* gb  = (const float*)d_in[5];
    const float* dw  = (const float*)d_in[6];
    const float* pw  = (const float*)d_in[7];
    const float* s1v = (const float*)d_in[8];
    const float* b1v = (const float*)d_in[9];
    const float* s2v = (const float*)d_in[10];
    const float* b2v = (const float*)d_in[11];
    float* out = (float*)d_out;

    ushort_t* An2T = (ushort_t*)d_ws;                       // 80*32
    ushort_t* W2   = An2T + 2560;                           // 64*192
    ushort_t* pw2  = W2 + 12288;                            // 64*64
    ushort_t* ybf  = (ushort_t*)((char*)d_ws + 65536);      // 64*12800*64 bf16 (~105 MB)

    k0_prep<<<1, 256, 0, stream>>>(Af, Al, Wg, pw, An2T, W2, pw2);
    k1_gcn<<<B_ * (T_ / 4), 256, 0, stream>>>(x, An2T, W2, gs, gb, ybf);
    k2_tcn<<<B_ * (T_ / 8), 256, 0, stream>>>(ybf, x, dw, pw2, s1v, b1v, s2v, b2v, out);
}

// Round 3
// 644.919 us; speedup vs baseline: 1.1238x; 1.0985x over previous
//
#include <hip/hip_runtime.h>
#include <math.h>

typedef unsigned short ushort_t;
typedef __attribute__((ext_vector_type(8))) short short8;
typedef __attribute__((ext_vector_type(4))) short short4v;
typedef __attribute__((ext_vector_type(4))) float f32x4;

#define B_ 64
#define C_ 64
#define T_ 512
#define V_ 25
#define K_ 3
#define O_ 64

__device__ __forceinline__ float hswish(float v) {
    return v * fminf(fmaxf(v + 3.0f, 0.0f), 6.0f) * (1.0f / 6.0f);
}
// round-to-nearest-even fp32 -> bf16 (values are finite, no NaN care)
__device__ __forceinline__ ushort_t f2bf(float f) {
    unsigned u = __float_as_uint(f);
    unsigned r = (u + 0x7FFFu + ((u >> 16) & 1u)) >> 16;
    return (ushort_t)r;
}
__device__ __forceinline__ float bf2f(ushort_t h) {
    return __uint_as_float(((unsigned)h) << 16);
}

// ---------------------------------------------------------------------------
// K0: build packed bf16 operands in workspace:
//   An2T[80][32]  : An2T[kw][v] = A_norm[k][v][w], kw=k*25+w (pad kw>=75, v>=25 -> 0)
//   W2  [64][192] : W2[o][k*64+c] = W_gcn[k][o][c] / 3
//   pw2 [64][64]  : pw2[o][c]    = tcn_pw[o][c]
// ---------------------------------------------------------------------------
__global__ void k0_prep(const float* __restrict__ Af, const float* __restrict__ Al,
                        const float* __restrict__ Wg, const float* __restrict__ pw,
                        ushort_t* __restrict__ An2T, ushort_t* __restrict__ W2,
                        ushort_t* __restrict__ pw2) {
    __shared__ float Aabs[K_ * V_ * V_];
    __shared__ float dsh[K_ * V_];
    int tid = threadIdx.x;
    for (int i = tid; i < K_ * V_ * V_; i += 256) Aabs[i] = fabsf(Af[i] + Al[i]);
    __syncthreads();
    for (int r = tid; r < K_ * V_; r += 256) {
        float s = 0.0f;
        for (int j = 0; j < V_; j++) s += Aabs[r * V_ + j];
        dsh[r] = rsqrtf(fmaxf(s, 1e-6f));
    }
    __syncthreads();
    for (int i = tid; i < 80 * 32; i += 256) {
        int kw = i >> 5, v = i & 31;
        float val = 0.0f;
        if (kw < 75 && v < 25) {
            int k = (kw >= 50) ? 2 : (kw >= 25 ? 1 : 0);
            int w = kw - k * 25;
            val = dsh[k * 25 + v] * Aabs[(k * 25 + v) * 25 + w] * dsh[k * 25 + w];
        }
        An2T[i] = f2bf(val);
    }
    for (int i = tid; i < 64 * 192; i += 256) {
        int o = i / 192, kc = i % 192;
        int k = kc >> 6, c = kc & 63;
        W2[i] = f2bf(Wg[(k * 64 + o) * 64 + c] * (1.0f / 3.0f));
    }
    for (int i = tid; i < 64 * 64; i += 256) pw2[i] = f2bf(pw[i]);
}

// ---------------------------------------------------------------------------
// K1: GCN, full MFMA. One block = one (b, 4 t's). 256 threads = 4 waves.
// stage0: x tile (1600 x 16B, linear) -> LDS via global_load_lds width=16
//         (dest offset = li*16 B = wave-uniform base + lane*16: HW-exact).
//         Loads issue back-to-back, drain at the barrier -- no reg round-trip.
// stage1: af frags from LDS; xa[(c,t) 256 x kw 80] = x-tile @ An2  (MFMA)
//         -> LDS xa2[tw 100][kc 192 (+8 pad)] bf16 (overlays stage0 buffer)
// stage2: y[o 64 x tw 100] = W2[64 x 192] @ xa2[192 x tw]  (MFMA), BN+hswish
// LDS 40.0 KB -> 4 blocks/CU (LDS-capped).
// ---------------------------------------------------------------------------
__global__ __launch_bounds__(256) void k1_gcn(
    const float* __restrict__ x, const ushort_t* __restrict__ An2T,
    const ushort_t* __restrict__ W2, const float* __restrict__ gs,
    const float* __restrict__ gb, ushort_t* __restrict__ y) {
    __shared__ ushort_t xa2[100 * 200];   // 40.0 KB (overlaid: first 25.6 KB = xs)
    float* xs = (float*)xa2;              // [64 c][100 floats]

    int bid = blockIdx.x;
    int b = bid >> 7;
    int t0 = (bid & 127) * 4;
    int tid = threadIdx.x;
    int wave = tid >> 6, lane = tid & 63;
    int m16 = lane & 15, g = lane >> 4;

    // ---- stage 0: async x -> LDS, 1600 dwordx4, linear LDS dest ----
    // guard li<1600 is wave-uniform (boundary at tid<64 on i=6)
#pragma unroll
    for (int i = 0; i < 7; i++) {
        int li = tid + 256 * i;
        if (li < 1600) {
            int c = li / 25, f4 = li % 25;
            const float* src = x + ((size_t)(b * 64 + c) * 512 + t0) * 25 + f4 * 4;
            __builtin_amdgcn_global_load_lds(
                (const __attribute__((address_space(1))) unsigned*)src,
                (__attribute__((address_space(3))) unsigned*)(xs + li * 4),
                16, 0, 0);
        }
    }

    // register-resident B-frags of An2 (5 N-tiles): B[v=g*8+j][kw=n*16+m16]
    short8 bfA[5];
#pragma unroll
    for (int n = 0; n < 5; n++)
        bfA[n] = *(const short8*)(An2T + (n * 16 + m16) * 32 + g * 8);

    __syncthreads();   // drains global_load_lds (vmcnt) + bfA

    // ---- read all A-frags from LDS BEFORE xa2 overwrites the buffer ----
    int v0 = g * 8;
    short8 af[4];
#pragma unroll
    for (int mt = 0; mt < 4; mt++) {
        int ct = (wave * 4 + mt) * 16 + m16;   // row = c*4 + t, addr = 25*ct + v
#pragma unroll
        for (int j = 0; j < 8; j++) {
            int v = v0 + j;
            float f = (v < 25) ? xs[25 * ct + v] : 0.0f;
            af[mt][j] = (short)f2bf(f);
        }
    }
    __syncthreads();   // xs dead; xa2 region may be written

    // ---- stage 1: MFMA + scatter to xa2 ----
#pragma unroll
    for (int mt = 0; mt < 4; mt++) {
        int Mt = wave * 4 + mt;
        f32x4 acc[5];
#pragma unroll
        for (int n = 0; n < 5; n++) {
            acc[n] = (f32x4){0.f, 0.f, 0.f, 0.f};
            acc[n] = __builtin_amdgcn_mfma_f32_16x16x32_bf16(af[mt], bfA[n], acc[n], 0, 0, 0);
        }
        // D layout: col kw = n*16+m16, row ct = Mt*16 + g*4 + r  => c = Mt*4+g, t = r
        int cc = Mt * 4 + g;
#pragma unroll
        for (int n = 0; n < 5; n++) {
            int kw = n * 16 + m16;
            if (kw < 75) {
                int k = (kw >= 50) ? 2 : (kw >= 25 ? 1 : 0);
                int w = kw - k * 25;
#pragma unroll
                for (int r = 0; r < 4; r++)
                    xa2[(r * 25 + w) * 200 + k * 64 + cc] = f2bf(acc[n][r]);
            }
        }
    }
    __syncthreads();

    // ---- stage 2 ----
    short8 afW[6];
#pragma unroll
    for (int kt = 0; kt < 6; kt++)
        afW[kt] = *(const short8*)(W2 + (wave * 16 + m16) * 192 + kt * 32 + g * 8);
    f32x4 gs4 = *(const f32x4*)(gs + wave * 16 + g * 4);
    f32x4 gb4 = *(const f32x4*)(gb + wave * 16 + g * 4);
    for (int nt = 0; nt < 7; nt++) {
        int tw = nt * 16 + m16;
        int twr = (tw < 100) ? tw : 99;   // clamped read; garbage cols masked at store
        f32x4 acc = (f32x4){0.f, 0.f, 0.f, 0.f};
#pragma unroll
        for (int kt = 0; kt < 6; kt++) {
            short8 bf = *(const short8*)(xa2 + twr * 200 + kt * 32 + g * 8);
            acc = __builtin_amdgcn_mfma_f32_16x16x32_bf16(afW[kt], bf, acc, 0, 0, 0);
        }
        if (tw < 100) {
            short4v pack;
#pragma unroll
            for (int r = 0; r < 4; r++) {
                float z = acc[r] * gs4[r] + gb4[r];
                pack[r] = (short)f2bf(hswish(z));
            }
            // y bf16 layout [b][tv][o], o = wave*16 + g*4 + r (4 consecutive)
            *(short4v*)(y + ((size_t)b * 12800 + t0 * 25 + tw) * 64 + wave * 16 + g * 4) = pack;
        }
    }
}

// ---------------------------------------------------------------------------
// K2: TCN. One block = one (b, 8 t's). 256 threads = 4 waves.
// phase A: stage y window (400 rows x 128 B) to LDS.
//          Interior tiles (62/64): global_load_lds width=16, linear dest
//          (offset = li*16 B), loads all issue then drain at the barrier.
//          Edge tiles: masked reg path with zero halo.
// phase B: depthwise k=9 + BN1 + hswish in registers (4 ch/thread, b64 reads)
// phase C: th overwrites same LDS buffer [tv 200][64] bf16
// phase D: pointwise 64x64 MFMA + BN2 + residual + hswish -> out fp32
//          (direct scattered epilogue: round-1 proven faster than LDS bounce;
//           the apparent WRITE_SIZE amplification is L2<->L3 traffic, L3-absorbed)
// LDS 51.2 KB -> 3 blocks/CU.
// ---------------------------------------------------------------------------
__global__ __launch_bounds__(256, 3) void k2_tcn(
    const ushort_t* __restrict__ y, const float* __restrict__ x,
    const float* __restrict__ dw, const ushort_t* __restrict__ pw2,
    const float* __restrict__ s1v, const float* __restrict__ b1v,
    const float* __restrict__ s2v, const float* __restrict__ b2v,
    float* __restrict__ out) {
    __shared__ ushort_t ys[400 * 64];   // 51.2 KB (reused for th)

    int bid = blockIdx.x;
    int b = bid >> 6;
    int t0 = (bid & 63) * 8;
    int tid = threadIdx.x;
    int wave = tid >> 6, lane = tid & 63;
    int m16 = lane & 15, g = lane >> 4;

    // ---- phase A: stage window rows [t0*25-100, t0*25+300) ----
    const ushort_t* yb = y + (size_t)b * 12800 * 64;
    int tvbase = t0 * 25 - 100;
    if (t0 != 0 && t0 != 504) {
        // interior: async direct-to-LDS, 3200 x 16B, linear in li
        const ushort_t* src0 = yb + (size_t)tvbase * 64;
#pragma unroll
        for (int i = 0; i < 13; i++) {
            int li = tid + 256 * i;      // guard wave-uniform (boundary tid<128 @ i=12)
            if (li < 3200) {
                __builtin_amdgcn_global_load_lds(
                    (const __attribute__((address_space(1))) unsigned*)(src0 + li * 8),
                    (__attribute__((address_space(3))) unsigned*)(ys + li * 8),
                    16, 0, 0);
            }
        }
    } else {
        // edge: masked reg path, zero halo
#pragma unroll
        for (int i = 0; i < 13; i++) {
            int li = tid + 256 * i;
            if (li < 3200) {
                int row = li >> 3;
                int col = (li & 7) * 8;
                int tvg = tvbase + row;
                short8 val = (short8){0, 0, 0, 0, 0, 0, 0, 0};
                if (tvg >= 0 && tvg < 12800)
                    val = *(const short8*)(yb + (size_t)tvg * 64 + col);
                *(short8*)(ys + row * 64 + col) = val;
            }
        }
    }
    __syncthreads();

    // ---- phase B: depthwise into registers ----
    int cg = tid & 15, c0 = cg * 4;
    float dwc[4][9], s1r[4], b1r[4];
#pragma unroll
    for (int cj = 0; cj < 4; cj++) {
#pragma unroll
        for (int dt = 0; dt < 9; dt++) dwc[cj][dt] = dw[(c0 + cj) * 9 + dt];
        s1r[cj] = s1v[c0 + cj];
        b1r[cj] = b1v[c0 + cj];
    }
    short4v thv[13];
#pragma unroll
    for (int i = 0; i < 13; i++) {
        int tv = (tid >> 4) + 16 * i;
        float a0 = 0, a1 = 0, a2 = 0, a3 = 0;
        if (tv < 200) {
#pragma unroll
            for (int dt = 0; dt < 9; dt++) {
                short4v yv = *(const short4v*)(ys + (tv + dt * 25) * 64 + c0);
                a0 += dwc[0][dt] * bf2f((ushort_t)yv[0]);
                a1 += dwc[1][dt] * bf2f((ushort_t)yv[1]);
                a2 += dwc[2][dt] * bf2f((ushort_t)yv[2]);
                a3 += dwc[3][dt] * bf2f((ushort_t)yv[3]);
            }
        }
        short4v p;
        p[0] = (short)f2bf(hswish(a0 * s1r[0] + b1r[0]));
        p[1] = (short)f2bf(hswish(a1 * s1r[1] + b1r[1]));
        p[2] = (short)f2bf(hswish(a2 * s1r[2] + b1r[2]));
        p[3] = (short)f2bf(hswish(a3 * s1r[3] + b1r[3]));
        thv[i] = p;
    }
    __syncthreads();   // all ys reads complete before overwrite

    // ---- phase C: th[tv][64] into same buffer ----
#pragma unroll
    for (int i = 0; i < 13; i++) {
        int tv = (tid >> 4) + 16 * i;
        if (tv < 200) *(short4v*)(ys + tv * 64 + c0) = thv[i];
    }
    __syncthreads();

    // ---- phase D: pointwise MFMA + direct epilogue ----
    short8 afP[2];
#pragma unroll
    for (int kt = 0; kt < 2; kt++)
        afP[kt] = *(const short8*)(pw2 + (wave * 16 + m16) * 64 + kt * 32 + g * 8);
    f32x4 s2_4 = *(const f32x4*)(s2v + wave * 16 + g * 4);
    f32x4 b2_4 = *(const f32x4*)(b2v + wave * 16 + g * 4);
    for (int nt = 0; nt < 13; nt++) {
        int tw = nt * 16 + m16;
        int twc = (tw < 200) ? tw : 199;   // clamped read; garbage cols masked at store
        f32x4 acc = (f32x4){0.f, 0.f, 0.f, 0.f};
#pragma unroll
        for (int kt = 0; kt < 2; kt++) {
            short8 bf = *(const short8*)(ys + twc * 64 + kt * 32 + g * 8);
            acc = __builtin_amdgcn_mfma_f32_16x16x32_bf16(afP[kt], bf, acc, 0, 0, 0);
        }
        if (tw < 200) {
#pragma unroll
            for (int r = 0; r < 4; r++) {
                int o = wave * 16 + g * 4 + r;
                size_t idx = (size_t)(b * 64 + o) * 12800 + t0 * 25 + tw;
                float z = acc[r] * s2_4[r] + b2_4[r] + x[idx];
                out[idx] = hswish(z);
            }
        }
    }
}

extern "C" void kernel_launch(void* const* d_in, const int* in_sizes, int n_in,
                              void* d_out, int out_size, void* d_ws, size_t ws_size,
                              hipStream_t stream) {
    const float* x   = (const float*)d_in[0];
    const float* Af  = (const float*)d_in[1];
    const float* Al  = (const float*)d_in[2];
    const float* Wg  = (const float*)d_in[3];
    const float* gs  = (const float*)d_in[4];
    const float* gb  = (const float*)d_in[5];
    const float* dw  = (const float*)d_in[6];
    const float* pw  = (const float*)d_in[7];
    const float* s1v = (const float*)d_in[8];
    const float* b1v = (const float*)d_in[9];
    const float* s2v = (const float*)d_in[10];
    const float* b2v = (const float*)d_in[11];
    float* out = (float*)d_out;

    ushort_t* An2T = (ushort_t*)d_ws;                       // 80*32
    ushort_t* W2   = An2T + 2560;                           // 64*192
    ushort_t* pw2  = W2 + 12288;                            // 64*64
    ushort_t* ybf  = (ushort_t*)((char*)d_ws + 65536);      // 64*12800*64 bf16 (~105 MB)

    k0_prep<<<1, 256, 0, stream>>>(Af, Al, Wg, pw, An2T, W2, pw2);
    k1_gcn<<<B_ * (T_ / 4), 256, 0, stream>>>(x, An2T, W2, gs, gb, ybf);
    k2_tcn<<<B_ * (T_ / 8), 256, 0, stream>>>(ybf, x, dw, pw2, s1v, b1v, s2v, b2v, out);
}